// Round 5
// baseline (305.529 us; speedup 1.0000x reference)
//
#include <hip/hip_runtime.h>

#define NN 50000
#define NE 800000
#define D  128

typedef _Float16 f16;
typedef _Float16 f16x4 __attribute__((ext_vector_type(4)));
typedef _Float16 f16x8 __attribute__((ext_vector_type(8)));
typedef float f32x4 __attribute__((ext_vector_type(4)));
typedef unsigned short u16;

// ---------------- prep: all f32->f16 converts + deg zeroing, one kernel ----------------
// blocks [0,6250): x (1.6M float4s); [6250,6346): 6 weight mats; [6346,6542): zero deg
__global__ __launch_bounds__(256) void prep(
    const float* __restrict__ x, f16* __restrict__ xf,
    const float* w0, const float* w1, const float* w2,
    const float* w3, const float* w4, const float* w5,
    f16* d0, f16* d1, f16* d2, f16* d3, f16* d4, f16* d5,
    int* __restrict__ deg) {
    int b = blockIdx.x;
    if (b < 6250) {
        int i = b * 256 + threadIdx.x;
        float4 v = ((const float4*)x)[i];
        f16x4 o = {(f16)v.x, (f16)v.y, (f16)v.z, (f16)v.w};
        ((f16x4*)xf)[i] = o;
    } else if (b < 6346) {
        int wb = b - 6250;
        int mat = wb >> 4;
        const float* s; f16* d;
        switch (mat) {
            case 0: s = w0; d = d0; break; case 1: s = w1; d = d1; break;
            case 2: s = w2; d = d2; break; case 3: s = w3; d = d3; break;
            case 4: s = w4; d = d4; break; default: s = w5; d = d5; break;
        }
        int i = (wb & 15) * 256 + threadIdx.x;   // 0..4095 float4
        float4 v = ((const float4*)s)[i];
        f16x4 o = {(f16)v.x, (f16)v.y, (f16)v.z, (f16)v.w};
        ((f16x4*)d)[i] = o;
    } else {
        int i = (b - 6346) * 256 + threadIdx.x;
        if (i < NN) deg[i] = 0;
    }
}

// ---------------- CSR build (2 edges/thread) ----------------

__global__ __launch_bounds__(256) void count_deg_rank(
    const int* __restrict__ row, int* __restrict__ deg, u16* __restrict__ rank, int e2) {
    int i = blockIdx.x * blockDim.x + threadIdx.x;
    if (i < e2) {
        int2 r = ((const int2*)row)[i];
        unsigned ra = (unsigned)atomicAdd(&deg[r.x], 1);
        unsigned rb = (unsigned)atomicAdd(&deg[r.y], 1);
        ((unsigned*)rank)[i] = (ra & 0xffffu) | (rb << 16);
    }
}

__global__ void scan_partial(const int* __restrict__ deg, int* __restrict__ bsum, int n) {
    __shared__ int s[1024];
    int i = blockIdx.x * 1024 + threadIdx.x;
    s[threadIdx.x] = (i < n) ? deg[i] : 0;
    __syncthreads();
    for (int off = 512; off > 0; off >>= 1) {
        if (threadIdx.x < off) s[threadIdx.x] += s[threadIdx.x + off];
        __syncthreads();
    }
    if (threadIdx.x == 0) bsum[blockIdx.x] = s[0];
}

// final scan with inline exclusive block-prefix (wave-reduce over bsum)
__global__ void scan_final(const int* __restrict__ deg, const int* __restrict__ bsum,
                           int* __restrict__ offsets, int n, int nb) {
    __shared__ int s[1024];
    __shared__ int base;
    if (threadIdx.x < 64) {
        int t = threadIdx.x;
        int v = (t < nb && t < (int)blockIdx.x) ? bsum[t] : 0;
#pragma unroll
        for (int m = 1; m < 64; m <<= 1) v += __shfl_xor(v, m, 64);
        if (t == 0) base = v;
    }
    int i = blockIdx.x * 1024 + threadIdx.x;
    int dv = (i < n) ? deg[i] : 0;
    s[threadIdx.x] = dv;
    __syncthreads();
    for (int off = 1; off < 1024; off <<= 1) {
        int t = (threadIdx.x >= (unsigned)off) ? s[threadIdx.x - off] : 0;
        __syncthreads();
        s[threadIdx.x] += t;
        __syncthreads();
    }
    if (i < n) {
        offsets[i + 1] = s[threadIdx.x] + base;
        if (i == 0) offsets[0] = 0;
    }
}

__global__ __launch_bounds__(256) void fill_csr(
    const int* __restrict__ row, const int* __restrict__ col,
    const u16* __restrict__ rank, const int* __restrict__ offsets,
    u16* __restrict__ csr_col, int e2) {
    int i = blockIdx.x * blockDim.x + threadIdx.x;
    if (i < e2) {
        int2 r = ((const int2*)row)[i];
        int2 c = ((const int2*)col)[i];
        unsigned rk = ((const unsigned*)rank)[i];
        csr_col[offsets[r.x] + (int)(rk & 0xffffu)] = (u16)c.x;
        csr_col[offsets[r.y] + (int)(rk >> 16)]     = (u16)c.y;
    }
}

// ---------------- mean aggregation ----------------
// 4 nodes per wave: sub = lane>>4 owns one node, its 16 lanes (fl) cover the
// 128 features as f16x8 (16B/lane -> 1KB gather per wave-instr, 4 rows).
// No cross-sub reduction. Accumulate packed f16 (pk_add), fp32 only at the
// mean. Predicated (exec-masked) loads handle degree divergence between subs.
template<int RELU>
__global__ __launch_bounds__(256) void aggregate_f16(
    const f16* __restrict__ h, const int* __restrict__ offsets,
    const u16* __restrict__ csr, f16* __restrict__ agg) {
    int wave = threadIdx.x >> 6;
    int lane = threadIdx.x & 63;
    int sub = lane >> 4, fl = lane & 15;
    int node = blockIdx.x * 16 + wave * 4 + sub;   // grid exact: 3125*16 = 50000
    int s0 = offsets[node];
    int dg = offsets[node + 1] - s0;

    int maxd = dg;
    maxd = max(maxd, __shfl_xor(maxd, 16, 64));
    maxd = max(maxd, __shfl_xor(maxd, 32, 64));

    f16x8 acc = {};
    const f16* hp = h + fl * 8;

    int it = 0;
    for (; it + 2 <= maxd; it += 2) {
        f16x8 v0 = {}, v1 = {};
        if (it < dg) {
            int c0 = (int)csr[s0 + it];
            v0 = *(const f16x8*)(hp + (size_t)c0 * D);
        }
        if (it + 1 < dg) {
            int c1 = (int)csr[s0 + it + 1];
            v1 = *(const f16x8*)(hp + (size_t)c1 * D);
        }
        if (RELU) {
#pragma unroll
            for (int u = 0; u < 8; ++u) {
                v0[u] = (v0[u] < (f16)0) ? (f16)0 : v0[u];
                v1[u] = (v1[u] < (f16)0) ? (f16)0 : v1[u];
            }
        }
        acc = acc + v0;
        acc = acc + v1;
    }
    if (it < maxd) {
        f16x8 v0 = {};
        if (it < dg) {
            int c0 = (int)csr[s0 + it];
            v0 = *(const f16x8*)(hp + (size_t)c0 * D);
        }
        if (RELU) {
#pragma unroll
            for (int u = 0; u < 8; ++u) v0[u] = (v0[u] < (f16)0) ? (f16)0 : v0[u];
        }
        acc = acc + v0;
    }

    float inv = 1.f / fmaxf((float)dg, 1.f);
    f16x8 o;
#pragma unroll
    for (int u = 0; u < 8; ++u) o[u] = (f16)((float)acc[u] * inv);
    *((f16x8*)(agg + (size_t)node * D) + fl) = o;
}

// ---------------- MFMA dual-GEMM, LDS-staged weights, 2-phase pipelined ----------------
#define WPAD 72   // 64 + 8 f16 pad -> 144B row stride, <=2-way bank aliasing

template<int RELU_X, int ADD_RES, int OUT_F32>
__global__ __launch_bounds__(256, 4) void sage_gemm_mfma(
    const f16* __restrict__ aggb, const f16* __restrict__ xb,
    const f16* __restrict__ Wl, const f16* __restrict__ Wr,
    const float* __restrict__ bias, float* __restrict__ outf,
    f16* __restrict__ outh) {
    __shared__ f16 sW[2][128][WPAD];   // 36864 B

    const int tid  = threadIdx.x;
    const int wave = tid >> 6;
    const int lane = tid & 63;
    const int lm = lane & 15;
    const int q  = lane >> 4;
    const int mt = blockIdx.x * 64 + wave * 16;

    int row = mt + lm;
    int rclamp = (row < NN) ? row : NN - 1;

    // A fragments (full K), relu on x inline
    f16x8 Aa[4], Ax[4];
    const f16* arow = aggb + (size_t)rclamp * D + q * 8;
    const f16* xrow = xb  + (size_t)rclamp * D + q * 8;
#pragma unroll
    for (int ks = 0; ks < 4; ++ks) {
        Aa[ks] = *(const f16x8*)(arow + ks * 32);
        f16x8 v = *(const f16x8*)(xrow + ks * 32);
        if (RELU_X) {
#pragma unroll
            for (int u = 0; u < 8; ++u) v[u] = (v[u] < (f16)0) ? (f16)0 : v[u];
        }
        Ax[ks] = v;
    }

    // prefetch phase-0 weights into registers
    f16x8 st[8];
#pragma unroll
    for (int it = 0; it < 8; ++it) {
        int idx = tid + it * 256;
        int mat = idx >> 10, n = (idx >> 3) & 127, c = idx & 7;
        const f16* W = mat ? Wr : Wl;
        st[it] = *(const f16x8*)(W + n * D + c * 8);
    }

    f32x4 acc[8];
#pragma unroll
    for (int nt = 0; nt < 8; ++nt) acc[nt] = (f32x4){0.f, 0.f, 0.f, 0.f};

#pragma unroll
    for (int p = 0; p < 2; ++p) {
        if (p) __syncthreads();          // previous phase's sW reads done
#pragma unroll
        for (int it = 0; it < 8; ++it) {
            int idx = tid + it * 256;
            int mat = idx >> 10, n = (idx >> 3) & 127, c = idx & 7;
            *(f16x8*)&sW[mat][n][c * 8] = st[it];
        }
        __syncthreads();
        if (p == 0) {                    // overlap phase-1 fetch with phase-0 MFMAs
#pragma unroll
            for (int it = 0; it < 8; ++it) {
                int idx = tid + it * 256;
                int mat = idx >> 10, n = (idx >> 3) & 127, c = idx & 7;
                const f16* W = mat ? Wr : Wl;
                st[it] = *(const f16x8*)(W + n * D + 64 + c * 8);
            }
        }
#pragma unroll
        for (int nt = 0; nt < 8; ++nt) {
#pragma unroll
            for (int k2 = 0; k2 < 2; ++k2) {
                f16x8 bl = *(const f16x8*)&sW[0][nt * 16 + lm][k2 * 32 + q * 8];
                acc[nt] = __builtin_amdgcn_mfma_f32_16x16x32_f16(Aa[p * 2 + k2], bl, acc[nt], 0, 0, 0);
                f16x8 br = *(const f16x8*)&sW[1][nt * 16 + lm][k2 * 32 + q * 8];
                acc[nt] = __builtin_amdgcn_mfma_f32_16x16x32_f16(Ax[p * 2 + k2], br, acc[nt], 0, 0, 0);
            }
        }
    }

    // epilogue: bias (+ f16 residual from xb). In-place outh==xb is safe.
#pragma unroll
    for (int nt = 0; nt < 8; ++nt) {
        int n = nt * 16 + lm;
        float bval = bias[n];
#pragma unroll
        for (int r = 0; r < 4; ++r) {
            int m = mt + q * 4 + r;
            if (m < NN) {
                size_t idx = (size_t)m * D + n;
                float v = acc[nt][r] + bval;
                if (ADD_RES) v += (float)xb[idx];
                if (OUT_F32) outf[idx] = v;
                else         outh[idx] = (f16)v;
            }
        }
    }
}

// ---------------- launch ----------------

extern "C" void kernel_launch(void* const* d_in, const int* in_sizes, int n_in,
                              void* d_out, int out_size, void* d_ws, size_t ws_size,
                              hipStream_t stream) {
    const float* x    = (const float*)d_in[0];
    const int*   erow = (const int*)d_in[1];
    const int*   ecol = (const int*)d_in[2];
    const float* Wl0 = (const float*)d_in[3];
    const float* Wr0 = (const float*)d_in[4];
    const float* b0  = (const float*)d_in[5];
    const float* Wl1 = (const float*)d_in[6];
    const float* Wr1 = (const float*)d_in[7];
    const float* b1  = (const float*)d_in[8];
    const float* Wl2 = (const float*)d_in[9];
    const float* Wr2 = (const float*)d_in[10];
    const float* b2  = (const float*)d_in[11];

    char* ws = (char*)d_ws;
    size_t off = 0;
    auto carve = [&](size_t bytes) -> void* {
        void* p = ws + off;
        off = (off + bytes + 255) & ~(size_t)255;
        return p;
    };
    int*   deg     = (int*)carve((size_t)NN * 4);
    int*   offsets = (int*)carve((size_t)(NN + 1) * 4);
    int*   bsum    = (int*)carve(64 * 4);
    u16*   rank    = (u16*)carve((size_t)NE * 2);
    u16*   csr_col = (u16*)carve((size_t)NE * 2);
    f16*   xf      = (f16*)carve((size_t)NN * D * 2);
    f16*   x1      = (f16*)carve((size_t)NN * D * 2);
    f16*   aggb    = (f16*)carve((size_t)NN * D * 2);
    f16*   wl0 = (f16*)carve(D * D * 2); f16* wr0 = (f16*)carve(D * D * 2);
    f16*   wl1 = (f16*)carve(D * D * 2); f16* wr1 = (f16*)carve(D * D * 2);
    f16*   wl2 = (f16*)carve(D * D * 2); f16* wr2 = (f16*)carve(D * D * 2);
    (void)ws_size; (void)in_sizes; (void)n_in; (void)out_size;

    float* outp = (float*)d_out;

    // prep: converts + deg zero (6250 + 96 + 196 blocks)
    prep<<<6542, 256, 0, stream>>>(x, xf, Wl0, Wr0, Wl1, Wr1, Wl2, Wr2,
                                   wl0, wr0, wl1, wr1, wl2, wr2, deg);

    // CSR build (2 edges per thread)
    const int e2 = NE / 2;
    count_deg_rank<<<(e2 + 255) / 256, 256, 0, stream>>>(erow, deg, rank, e2);
    const int nsb = (NN + 1023) / 1024;   // 49
    scan_partial<<<nsb, 1024, 0, stream>>>(deg, bsum, NN);
    scan_final<<<nsb, 1024, 0, stream>>>(deg, bsum, offsets, NN, nsb);
    fill_csr<<<(e2 + 255) / 256, 256, 0, stream>>>(erow, ecol, rank, offsets, csr_col, e2);

    const int agrid = NN / 16;              // 3125, exact
    const int ggrid = (NN + 63) / 64;       // 782

    // layer 0: x1 = agg(xf)@Wl0^T + xf@Wr0^T + b0   (f16 state, pre-relu)
    aggregate_f16<0><<<agrid, 256, 0, stream>>>(xf, offsets, csr_col, aggb);
    sage_gemm_mfma<0, 0, 0><<<ggrid, 256, 0, stream>>>(aggb, xf, wl0, wr0, b0,
                                                       nullptr, x1);
    // layer 1: x1 = agg(relu(x1))@Wl1^T + relu(x1)@Wr1^T + b1 + x1  (in place)
    aggregate_f16<1><<<agrid, 256, 0, stream>>>(x1, offsets, csr_col, aggb);
    sage_gemm_mfma<1, 1, 0><<<ggrid, 256, 0, stream>>>(aggb, x1, wl1, wr1, b1,
                                                       nullptr, x1);
    // layer 2: out = agg(relu(x1))@Wl2^T + relu(x1)@Wr2^T + b2 + x1  (fp32)
    aggregate_f16<1><<<agrid, 256, 0, stream>>>(x1, offsets, csr_col, aggb);
    sage_gemm_mfma<1, 1, 1><<<ggrid, 256, 0, stream>>>(aggb, x1, wl2, wr2, b2,
                                                       outp, nullptr);
}

// Round 6
// 278.961 us; speedup vs baseline: 1.0952x; 1.0952x over previous
//
#include <hip/hip_runtime.h>

#define NN 50000
#define NE 800000
#define D  128

typedef _Float16 f16;
typedef _Float16 f16x4 __attribute__((ext_vector_type(4)));
typedef _Float16 f16x8 __attribute__((ext_vector_type(8)));
typedef float f32x4 __attribute__((ext_vector_type(4)));
typedef float f32x2 __attribute__((ext_vector_type(2)));
typedef unsigned short u16;
typedef unsigned int u32;
typedef unsigned char u8;

// ---------------- prep: f32->f16 + f32->fp8 converts + deg zeroing ----------------
// blocks [0,6250): x -> xf (f16) and xf8 (fp8); [6250,6346): 6 weight mats; rest: zero deg
__global__ __launch_bounds__(256) void prep(
    const float* __restrict__ x, f16* __restrict__ xf, u8* __restrict__ xf8,
    const float* w0, const float* w1, const float* w2,
    const float* w3, const float* w4, const float* w5,
    f16* d0, f16* d1, f16* d2, f16* d3, f16* d4, f16* d5,
    int* __restrict__ deg) {
    int b = blockIdx.x;
    if (b < 6250) {
        int i = b * 256 + threadIdx.x;
        float4 v = ((const float4*)x)[i];
        f16x4 o = {(f16)v.x, (f16)v.y, (f16)v.z, (f16)v.w};
        ((f16x4*)xf)[i] = o;
        u32 lo = __builtin_amdgcn_cvt_pk_fp8_f32(v.x, v.y, 0, false);
        u32 pk = __builtin_amdgcn_cvt_pk_fp8_f32(v.z, v.w, lo, true);
        ((u32*)xf8)[i] = pk;
    } else if (b < 6346) {
        int wb = b - 6250;
        int mat = wb >> 4;
        const float* s; f16* d;
        switch (mat) {
            case 0: s = w0; d = d0; break; case 1: s = w1; d = d1; break;
            case 2: s = w2; d = d2; break; case 3: s = w3; d = d3; break;
            case 4: s = w4; d = d4; break; default: s = w5; d = d5; break;
        }
        int i = (wb & 15) * 256 + threadIdx.x;   // 0..4095 float4
        float4 v = ((const float4*)s)[i];
        f16x4 o = {(f16)v.x, (f16)v.y, (f16)v.z, (f16)v.w};
        ((f16x4*)d)[i] = o;
    } else {
        int i = (b - 6346) * 256 + threadIdx.x;
        if (i < NN) deg[i] = 0;
    }
}

// ---------------- CSR build ----------------

__global__ __launch_bounds__(256) void count_deg_rank(
    const int* __restrict__ row, int* __restrict__ deg, u16* __restrict__ rank, int e) {
    int i = blockIdx.x * blockDim.x + threadIdx.x;
    if (i < e) rank[i] = (u16)atomicAdd(&deg[row[i]], 1);
}

__global__ void scan_partial(const int* __restrict__ deg, int* __restrict__ bsum, int n) {
    __shared__ int s[1024];
    int i = blockIdx.x * 1024 + threadIdx.x;
    s[threadIdx.x] = (i < n) ? deg[i] : 0;
    __syncthreads();
    for (int off = 512; off > 0; off >>= 1) {
        if (threadIdx.x < off) s[threadIdx.x] += s[threadIdx.x + off];
        __syncthreads();
    }
    if (threadIdx.x == 0) bsum[blockIdx.x] = s[0];
}

// final scan with inline exclusive block-prefix (wave-reduce over bsum)
__global__ void scan_final(const int* __restrict__ deg, const int* __restrict__ bsum,
                           int* __restrict__ offsets, int n, int nb) {
    __shared__ int s[1024];
    __shared__ int base;
    if (threadIdx.x < 64) {
        int t = threadIdx.x;
        int v = (t < nb && t < (int)blockIdx.x) ? bsum[t] : 0;
#pragma unroll
        for (int m = 1; m < 64; m <<= 1) v += __shfl_xor(v, m, 64);
        if (t == 0) base = v;
    }
    int i = blockIdx.x * 1024 + threadIdx.x;
    int dv = (i < n) ? deg[i] : 0;
    s[threadIdx.x] = dv;
    __syncthreads();
    for (int off = 1; off < 1024; off <<= 1) {
        int t = (threadIdx.x >= (unsigned)off) ? s[threadIdx.x - off] : 0;
        __syncthreads();
        s[threadIdx.x] += t;
        __syncthreads();
    }
    if (i < n) {
        offsets[i + 1] = s[threadIdx.x] + base;
        if (i == 0) offsets[0] = 0;
    }
}

__global__ __launch_bounds__(256) void fill_csr(
    const int* __restrict__ row, const int* __restrict__ col,
    const u16* __restrict__ rank, const int* __restrict__ offsets,
    u16* __restrict__ csr_col, int e) {
    int i = blockIdx.x * blockDim.x + threadIdx.x;
    if (i < e) {
        int p = offsets[row[i]] + (int)rank[i];
        csr_col[p] = (u16)col[i];
    }
}

// ---------------- mean aggregation (fp8 gather, fp32 accumulate) ----------------
// One wave per node; sub = lane>>4 is the edge slot (4 edges/load-instr),
// fl = lane&15 the feature octet: 8B fp8 per lane -> 128B/row, 512B/wave-instr.
// fp8 rows are stored POST-relu (written by gemm epilogue / prep), so no relu here.
// Unpack via v_cvt_pk_f32_fp8; cross-slot shuffle reduction at the end.
__global__ __launch_bounds__(256) void aggregate_f8(
    const u8* __restrict__ h8, const int* __restrict__ offsets,
    const u16* __restrict__ csr, f16* __restrict__ agg) {
    int node = blockIdx.x * 4 + (threadIdx.x >> 6);
    int lane = threadIdx.x & 63;
    int sub = lane >> 4, fl = lane & 15;
    int s0 = offsets[node], e0 = offsets[node + 1];
    int deg = e0 - s0;

    float acc[8];
#pragma unroll
    for (int u = 0; u < 8; ++u) acc[u] = 0.f;

    const u8* hp = h8 + fl * 8;

#define UNPACK_ADD(w)                                                  \
    do {                                                               \
        f32x2 p;                                                       \
        p = __builtin_amdgcn_cvt_pk_f32_fp8((w).x, false);             \
        acc[0] += p.x; acc[1] += p.y;                                  \
        p = __builtin_amdgcn_cvt_pk_f32_fp8((w).x, true);              \
        acc[2] += p.x; acc[3] += p.y;                                  \
        p = __builtin_amdgcn_cvt_pk_f32_fp8((w).y, false);             \
        acc[4] += p.x; acc[5] += p.y;                                  \
        p = __builtin_amdgcn_cvt_pk_f32_fp8((w).y, true);              \
        acc[6] += p.x; acc[7] += p.y;                                  \
    } while (0)

    int j = s0 + sub;
    for (int it = deg >> 3; it > 0; --it, j += 8) {
        int c0 = (int)csr[j];
        int c1 = (int)csr[j + 4];
        uint2 w0 = *(const uint2*)(hp + (size_t)c0 * D);
        uint2 w1 = *(const uint2*)(hp + (size_t)c1 * D);
        UNPACK_ADD(w0);
        UNPACK_ADD(w1);
    }
    if (deg & 4) {
        int c = (int)csr[j];
        uint2 w = *(const uint2*)(hp + (size_t)c * D);
        UNPACK_ADD(w);
        j += 4;
    }
    if (sub < (deg & 3)) {
        int c = (int)csr[j];
        uint2 w = *(const uint2*)(hp + (size_t)c * D);
        UNPACK_ADD(w);
    }
#undef UNPACK_ADD

    // reduce across the 4 edge slots (lanes l, l^16, l^32, l^48)
#pragma unroll
    for (int u = 0; u < 8; ++u) {
        acc[u] += __shfl_xor(acc[u], 16, 64);
        acc[u] += __shfl_xor(acc[u], 32, 64);
    }
    if (sub == 0) {
        float inv = 1.f / fmaxf((float)deg, 1.f);
        f16x8 o;
#pragma unroll
        for (int u = 0; u < 8; ++u) o[u] = (f16)(acc[u] * inv);
        *((f16x8*)(agg + (size_t)node * D) + fl) = o;
    }
}

// ---------------- MFMA dual-GEMM, LDS-staged weights ----------------
// out[m][n] = sum_k agg[m][k]*Wl[n][k] + relu?(x[m][k])*Wr[n][k] + b[n] (+ x[m][n])
// When !OUT_F32 also writes out8 = fp8(relu(out)) for the next layer's gather.
#define WPAD 72   // 64 + 8 f16 pad -> 144B row stride, <=2-way bank aliasing

template<int RELU_X, int ADD_RES, int OUT_F32>
__global__ __launch_bounds__(256, 4) void sage_gemm_mfma(
    const f16* __restrict__ aggb, const f16* __restrict__ xb,
    const f16* __restrict__ Wl, const f16* __restrict__ Wr,
    const float* __restrict__ bias, float* __restrict__ outf,
    f16* __restrict__ outh, u8* __restrict__ out8) {
    __shared__ f16 sW[2][128][WPAD];   // 36864 B

    const int tid  = threadIdx.x;
    const int wave = tid >> 6;
    const int lane = tid & 63;
    const int lm = lane & 15;
    const int q  = lane >> 4;
    const int mt = blockIdx.x * 64 + wave * 16;

    int row = mt + lm;
    int rclamp = (row < NN) ? row : NN - 1;

    // A fragments (full K), relu on x inline
    f16x8 Aa[4], Ax[4];
    const f16* arow = aggb + (size_t)rclamp * D + q * 8;
    const f16* xrow = xb  + (size_t)rclamp * D + q * 8;
#pragma unroll
    for (int ks = 0; ks < 4; ++ks) {
        Aa[ks] = *(const f16x8*)(arow + ks * 32);
        f16x8 v = *(const f16x8*)(xrow + ks * 32);
        if (RELU_X) {
#pragma unroll
            for (int u = 0; u < 8; ++u) v[u] = (v[u] < (f16)0) ? (f16)0 : v[u];
        }
        Ax[ks] = v;
    }

    f32x4 acc[8];
#pragma unroll
    for (int nt = 0; nt < 8; ++nt) acc[nt] = (f32x4){0.f, 0.f, 0.f, 0.f};

    for (int p = 0; p < 2; ++p) {
        __syncthreads();
        // stage Wl/Wr K-half: 2 mats x 128 n x 8 chunks of 16B = 2048 chunks
#pragma unroll
        for (int it = 0; it < 8; ++it) {
            int idx = tid + it * 256;
            int mat = idx >> 10;
            int n   = (idx >> 3) & 127;
            int c   = idx & 7;
            const f16* W = mat ? Wr : Wl;
            f16x8 v = *(const f16x8*)(W + n * D + p * 64 + c * 8);
            *(f16x8*)&sW[mat][n][c * 8] = v;
        }
        __syncthreads();

#pragma unroll
        for (int nt = 0; nt < 8; ++nt) {
#pragma unroll
            for (int k2 = 0; k2 < 2; ++k2) {
                f16x8 bl = *(const f16x8*)&sW[0][nt * 16 + lm][k2 * 32 + q * 8];
                acc[nt] = __builtin_amdgcn_mfma_f32_16x16x32_f16(Aa[p * 2 + k2], bl, acc[nt], 0, 0, 0);
                f16x8 br = *(const f16x8*)&sW[1][nt * 16 + lm][k2 * 32 + q * 8];
                acc[nt] = __builtin_amdgcn_mfma_f32_16x16x32_f16(Ax[p * 2 + k2], br, acc[nt], 0, 0, 0);
            }
        }
    }

    // epilogue: bias (+ f16 residual from xb). In-place outh==xb is safe:
    // each (m,n) is read & written by exactly one lane, rows owned by this wave.
#pragma unroll
    for (int nt = 0; nt < 8; ++nt) {
        int n = nt * 16 + lm;
        float bval = bias[n];
#pragma unroll
        for (int r = 0; r < 4; ++r) {
            int m = mt + q * 4 + r;
            if (m < NN) {
                size_t idx = (size_t)m * D + n;
                float v = acc[nt][r] + bval;
                if (ADD_RES) v += (float)xb[idx];
                if (OUT_F32) {
                    outf[idx] = v;
                } else {
                    outh[idx] = (f16)v;
                    u32 t = __builtin_amdgcn_cvt_pk_fp8_f32(fmaxf(v, 0.f), 0.f, 0, false);
                    out8[idx] = (u8)(t & 0xffu);
                }
            }
        }
    }
}

// ---------------- launch ----------------

extern "C" void kernel_launch(void* const* d_in, const int* in_sizes, int n_in,
                              void* d_out, int out_size, void* d_ws, size_t ws_size,
                              hipStream_t stream) {
    const float* x    = (const float*)d_in[0];
    const int*   erow = (const int*)d_in[1];
    const int*   ecol = (const int*)d_in[2];
    const float* Wl0 = (const float*)d_in[3];
    const float* Wr0 = (const float*)d_in[4];
    const float* b0  = (const float*)d_in[5];
    const float* Wl1 = (const float*)d_in[6];
    const float* Wr1 = (const float*)d_in[7];
    const float* b1  = (const float*)d_in[8];
    const float* Wl2 = (const float*)d_in[9];
    const float* Wr2 = (const float*)d_in[10];
    const float* b2  = (const float*)d_in[11];

    char* ws = (char*)d_ws;
    size_t off = 0;
    auto carve = [&](size_t bytes) -> void* {
        void* p = ws + off;
        off = (off + bytes + 255) & ~(size_t)255;
        return p;
    };
    int*   deg     = (int*)carve((size_t)NN * 4);
    int*   offsets = (int*)carve((size_t)(NN + 1) * 4);
    int*   bsum    = (int*)carve(64 * 4);
    u16*   rank    = (u16*)carve((size_t)NE * 2);
    u16*   csr_col = (u16*)carve((size_t)NE * 2);
    f16*   xf      = (f16*)carve((size_t)NN * D * 2);
    f16*   x1      = (f16*)carve((size_t)NN * D * 2);
    f16*   aggb    = (f16*)carve((size_t)NN * D * 2);
    u8*    xf8     = (u8*)carve((size_t)NN * D);
    u8*    x1f8    = (u8*)carve((size_t)NN * D);
    f16*   wl0 = (f16*)carve(D * D * 2); f16* wr0 = (f16*)carve(D * D * 2);
    f16*   wl1 = (f16*)carve(D * D * 2); f16* wr1 = (f16*)carve(D * D * 2);
    f16*   wl2 = (f16*)carve(D * D * 2); f16* wr2 = (f16*)carve(D * D * 2);
    (void)ws_size; (void)in_sizes; (void)n_in; (void)out_size;

    float* outp = (float*)d_out;

    // prep: converts + deg zero (6250 + 96 + 196 blocks)
    prep<<<6542, 256, 0, stream>>>(x, xf, xf8, Wl0, Wr0, Wl1, Wr1, Wl2, Wr2,
                                   wl0, wr0, wl1, wr1, wl2, wr2, deg);

    // CSR build
    count_deg_rank<<<(NE + 255) / 256, 256, 0, stream>>>(erow, deg, rank, NE);
    const int nsb = (NN + 1023) / 1024;   // 49
    scan_partial<<<nsb, 1024, 0, stream>>>(deg, bsum, NN);
    scan_final<<<nsb, 1024, 0, stream>>>(deg, bsum, offsets, NN, nsb);
    fill_csr<<<(NE + 255) / 256, 256, 0, stream>>>(erow, ecol, rank, offsets, csr_col, NE);

    const int agrid = NN / 4;               // 12500, exact
    const int ggrid = (NN + 63) / 64;       // 782

    // layer 0: x1 = agg(x)@Wl0^T + x@Wr0^T + b0; x1f8 = fp8(relu(x1))
    aggregate_f8<<<agrid, 256, 0, stream>>>(xf8, offsets, csr_col, aggb);
    sage_gemm_mfma<0, 0, 0><<<ggrid, 256, 0, stream>>>(aggb, xf, wl0, wr0, b0,
                                                       nullptr, x1, x1f8);
    // layer 1: x1 = agg(relu(x1))@Wl1^T + relu(x1)@Wr1^T + b1 + x1  (in place)
    aggregate_f8<<<agrid, 256, 0, stream>>>(x1f8, offsets, csr_col, aggb);
    sage_gemm_mfma<1, 1, 0><<<ggrid, 256, 0, stream>>>(aggb, x1, wl1, wr1, b1,
                                                       nullptr, x1, x1f8);
    // layer 2: out = agg(relu(x1))@Wl2^T + relu(x1)@Wr2^T + b2 + x1  (fp32)
    aggregate_f8<<<agrid, 256, 0, stream>>>(x1f8, offsets, csr_col, aggb);
    sage_gemm_mfma<1, 1, 1><<<ggrid, 256, 0, stream>>>(aggb, x1, wl2, wr2, b2,
                                                       outp, nullptr, nullptr);
}